// Round 2
// baseline (1806.316 us; speedup 1.0000x reference)
//
#include <hip/hip_runtime.h>

#define BATCH 16384
#define NF 26
#define NTAB 100000
#define DIM 64
#define NLOOK 4
#define NFEAT 27
#define NPAIRS 351
#define YDIM 415

__device__ __forceinline__ void fma4(float4& acc, float s, const float4 w) {
    acc.x = fmaf(s, w.x, acc.x);
    acc.y = fmaf(s, w.y, acc.y);
    acc.z = fmaf(s, w.z, acc.z);
    acc.w = fmaf(s, w.w, acc.w);
}

// ---------------- K1: fused bottom MLP: 13 -> 512 -> 256 -> 64 (relu all) ----
__global__ __launch_bounds__(256) void bot_mlp_kernel(
    const float* __restrict__ x,
    const float* __restrict__ W0, const float* __restrict__ b0,
    const float* __restrict__ W1, const float* __restrict__ b1,
    const float* __restrict__ W2, const float* __restrict__ b2,
    float* __restrict__ feats, float* __restrict__ y)
{
    __shared__ float sx[16 * 13];
    __shared__ float sh0[16 * 512];
    __shared__ float sh1[16 * 256];
    const int t = threadIdx.x;
    const int r0 = blockIdx.x * 16;

    for (int i = t; i < 16 * 13; i += 256) sx[i] = x[(size_t)r0 * 13 + i];
    __syncthreads();

    // L0: 16x512 outputs, K=13
    for (int o = t; o < 16 * 512; o += 256) {
        int r = o >> 9, c = o & 511;
        float acc = b0[c];
        #pragma unroll
        for (int k = 0; k < 13; ++k) acc = fmaf(sx[r * 13 + k], W0[k * 512 + c], acc);
        sh0[o] = fmaxf(acc, 0.0f);
    }
    __syncthreads();

    // L1: 16x256 outputs, K=512. 64 threads/row-cols (float4), 4 rows in flight.
    {
        const int c4 = (t & 63) << 2;
        const int rsub = t >> 6;
        for (int r = rsub; r < 16; r += 4) {
            float4 acc = *(const float4*)&b1[c4];
            const float* hrow = &sh0[r * 512];
            #pragma unroll 4
            for (int k = 0; k < 512; k += 4) {
                float4 h = *(const float4*)&hrow[k];
                float4 w0 = *(const float4*)&W1[(k + 0) * 256 + c4];
                float4 w1 = *(const float4*)&W1[(k + 1) * 256 + c4];
                float4 w2 = *(const float4*)&W1[(k + 2) * 256 + c4];
                float4 w3 = *(const float4*)&W1[(k + 3) * 256 + c4];
                fma4(acc, h.x, w0);
                fma4(acc, h.y, w1);
                fma4(acc, h.z, w2);
                fma4(acc, h.w, w3);
            }
            float* o = &sh1[r * 256 + c4];
            o[0] = fmaxf(acc.x, 0.0f);
            o[1] = fmaxf(acc.y, 0.0f);
            o[2] = fmaxf(acc.z, 0.0f);
            o[3] = fmaxf(acc.w, 0.0f);
        }
    }
    __syncthreads();

    // L2: 16x64 outputs, K=256
    for (int o = t; o < 16 * 64; o += 256) {
        int r = o >> 6, c = o & 63;
        float acc = b2[c];
        const float* hrow = &sh1[r * 256];
        #pragma unroll 4
        for (int k = 0; k < 256; k += 4) {
            float4 h = *(const float4*)&hrow[k];
            acc = fmaf(h.x, W2[(k + 0) * 64 + c], acc);
            acc = fmaf(h.y, W2[(k + 1) * 64 + c], acc);
            acc = fmaf(h.z, W2[(k + 2) * 64 + c], acc);
            acc = fmaf(h.w, W2[(k + 3) * 64 + c], acc);
        }
        acc = fmaxf(acc, 0.0f);
        const size_t rg = (size_t)(r0 + r);
        feats[rg * (NFEAT * DIM) + c] = acc;   // slot 0 of feats
        y[rg * YDIM + c] = acc;                // first 64 of y
    }
}

// ---------------- K2: embedding gather + pool (sum over 4 lookups) ----------
__global__ __launch_bounds__(256) void embed_pool_kernel(
    const int* __restrict__ sidx, const float* __restrict__ tables,
    float* __restrict__ feats)
{
    const int wid = blockIdx.x * 4 + (threadIdx.x >> 6); // global wave id = f*B + b
    const int lane = threadIdx.x & 63;
    const int f = wid >> 14;          // B = 16384 = 2^14
    const int b = wid & 16383;
    const int* ip = sidx + (size_t)wid * NLOOK;
    const float* tab = tables + (size_t)f * NTAB * DIM;
    int i0 = ip[0], i1 = ip[1], i2 = ip[2], i3 = ip[3];
    float v0 = tab[(size_t)i0 * DIM + lane];
    float v1 = tab[(size_t)i1 * DIM + lane];
    float v2 = tab[(size_t)i2 * DIM + lane];
    float v3 = tab[(size_t)i3 * DIM + lane];
    feats[((size_t)b * NFEAT + 1 + f) * DIM + lane] = (v0 + v1) + (v2 + v3);
}

// ---------------- K3: pairwise interaction -> y[:, 64:415] -----------------
// LDS row stride padded to 68 floats to spread banks on the j-indexed reads.
__global__ __launch_bounds__(256) void interact_kernel(
    const float* __restrict__ feats, float* __restrict__ y)
{
    __shared__ float sf[4 * NFEAT * 68]; // 4*27*68*4B = 29376 B
    const int t = threadIdx.x;
    const size_t r0 = (size_t)blockIdx.x * 4;

    for (int i = t; i < 4 * NFEAT * DIM; i += 256) {
        int r = i / (NFEAT * DIM);
        int e = i - r * (NFEAT * DIM);
        int fi = e >> 6, d = e & 63;
        sf[r * (NFEAT * 68) + fi * 68 + d] = feats[r0 * (NFEAT * DIM) + i];
    }
    __syncthreads();

    for (int w = t; w < 4 * NPAIRS; w += 256) {
        int r = w / NPAIRS, p = w - r * NPAIRS;
        int i = 0, pp = p;
        while (pp >= NF - i) { pp -= NF - i; ++i; }
        int j = i + 1 + pp;
        const float* fa = &sf[r * (NFEAT * 68) + i * 68];
        const float* fb = &sf[r * (NFEAT * 68) + j * 68];
        float acc = 0.0f;
        #pragma unroll
        for (int k = 0; k < DIM; k += 4) {
            float4 a = *(const float4*)&fa[k];
            float4 bv = *(const float4*)&fb[k];
            acc = fmaf(a.x, bv.x, acc);
            acc = fmaf(a.y, bv.y, acc);
            acc = fmaf(a.z, bv.z, acc);
            acc = fmaf(a.w, bv.w, acc);
        }
        y[(r0 + r) * YDIM + DIM + p] = acc;
    }
}

// ---------------- K4/K5: generic row-tiled fp32 GEMM + bias (+relu) --------
template<int K, int KP, int NC, bool RELU>
__global__ __launch_bounds__(256) void mlp_gemm_kernel(
    const float* __restrict__ X, const float* __restrict__ W,
    const float* __restrict__ bias, float* __restrict__ out)
{
    __shared__ float sx[16 * KP];
    const int t = threadIdx.x;
    const size_t r0 = (size_t)blockIdx.x * 16;

    if (K == KP) {
        const float4* src = (const float4*)(X + r0 * K);
        for (int i = t; i < 16 * K / 4; i += 256) ((float4*)sx)[i] = src[i];
    } else {
        for (int i = t; i < 16 * K; i += 256) {
            int r = i / K, c = i - r * K;
            sx[r * KP + c] = X[r0 * K + i];
        }
    }
    __syncthreads();

    constexpr int TPR = NC / 4;     // threads covering one row's columns
    constexpr int RIF = 256 / TPR;  // rows in flight
    const int c4 = (t % TPR) * 4;
    const int rsub = t / TPR;

    for (int r = rsub; r < 16; r += RIF) {
        float4 acc = *(const float4*)&bias[c4];
        const float* hrow = &sx[r * KP];
        int k = 0;
        #pragma unroll 4
        for (; k + 4 <= K; k += 4) {
            float4 h = *(const float4*)&hrow[k];
            float4 w0 = *(const float4*)&W[(size_t)(k + 0) * NC + c4];
            float4 w1 = *(const float4*)&W[(size_t)(k + 1) * NC + c4];
            float4 w2 = *(const float4*)&W[(size_t)(k + 2) * NC + c4];
            float4 w3 = *(const float4*)&W[(size_t)(k + 3) * NC + c4];
            fma4(acc, h.x, w0);
            fma4(acc, h.y, w1);
            fma4(acc, h.z, w2);
            fma4(acc, h.w, w3);
        }
        for (; k < K; ++k) {
            float4 w = *(const float4*)&W[(size_t)k * NC + c4];
            fma4(acc, hrow[k], w);
        }
        if (RELU) {
            acc.x = fmaxf(acc.x, 0.0f);
            acc.y = fmaxf(acc.y, 0.0f);
            acc.z = fmaxf(acc.z, 0.0f);
            acc.w = fmaxf(acc.w, 0.0f);
        }
        *(float4*)&out[(r0 + r) * NC + c4] = acc;
    }
}

// ---------------- K6: final 256 -> 1 layer (no relu) ------------------------
__global__ __launch_bounds__(256) void top_final_kernel(
    const float* __restrict__ t1, const float* __restrict__ W2,
    const float* __restrict__ b2, float* __restrict__ out)
{
    const int wid = blockIdx.x * 4 + (threadIdx.x >> 6); // row
    const int lane = threadIdx.x & 63;
    const float4 w = ((const float4*)W2)[lane];
    const float4 v = ((const float4*)(t1 + (size_t)wid * 256))[lane];
    float acc = fmaf(v.x, w.x, fmaf(v.y, w.y, fmaf(v.z, w.z, v.w * w.w)));
    #pragma unroll
    for (int off = 32; off > 0; off >>= 1) acc += __shfl_down(acc, off, 64);
    if (lane == 0) out[wid] = acc + b2[0];
}

extern "C" void kernel_launch(void* const* d_in, const int* in_sizes, int n_in,
                              void* d_out, int out_size, void* d_ws, size_t ws_size,
                              hipStream_t stream)
{
    const float* dense = (const float*)d_in[0];
    const int*   sidx  = (const int*)d_in[1];
    const float* tabs  = (const float*)d_in[2];
    const float* bW0 = (const float*)d_in[3];  const float* bb0 = (const float*)d_in[4];
    const float* bW1 = (const float*)d_in[5];  const float* bb1 = (const float*)d_in[6];
    const float* bW2 = (const float*)d_in[7];  const float* bb2 = (const float*)d_in[8];
    const float* tW0 = (const float*)d_in[9];  const float* tb0 = (const float*)d_in[10];
    const float* tW1 = (const float*)d_in[11]; const float* tb1 = (const float*)d_in[12];
    const float* tW2 = (const float*)d_in[13]; const float* tb2 = (const float*)d_in[14];
    float* out = (float*)d_out;

    float* ws    = (float*)d_ws;
    float* feats = ws;                                   // B*27*64
    float* y     = feats + (size_t)BATCH * NFEAT * DIM;  // B*415
    float* t0    = y     + (size_t)BATCH * YDIM;         // B*512
    float* t1    = t0    + (size_t)BATCH * 512;          // B*256

    // Longest (memory-bound) kernel first.
    embed_pool_kernel<<<dim3(NF * BATCH / 4), dim3(256), 0, stream>>>(sidx, tabs, feats);
    bot_mlp_kernel<<<dim3(BATCH / 16), dim3(256), 0, stream>>>(
        dense, bW0, bb0, bW1, bb1, bW2, bb2, feats, y);
    interact_kernel<<<dim3(BATCH / 4), dim3(256), 0, stream>>>(feats, y);
    mlp_gemm_kernel<415, 416, 512, true><<<dim3(BATCH / 16), dim3(256), 0, stream>>>(y, tW0, tb0, t0);
    mlp_gemm_kernel<512, 512, 256, true><<<dim3(BATCH / 16), dim3(256), 0, stream>>>(t0, tW1, tb1, t1);
    top_final_kernel<<<dim3(BATCH / 4), dim3(256), 0, stream>>>(t1, tW2, tb2, out);
}

// Round 4
// 1696.235 us; speedup vs baseline: 1.0649x; 1.0649x over previous
//
#include <hip/hip_runtime.h>

#define BATCH 16384
#define NF 26
#define NTAB 100000
#define DIM 64
#define NFEAT 27
#define NPAIRS 351
#define YS 416   // padded y row stride (float4-aligned, 13 chunks of 32)
#define YK 415   // true K of top layer 0

__device__ __forceinline__ void fma4(float4& acc, float s, const float4 w) {
    acc.x = fmaf(s, w.x, acc.x);
    acc.y = fmaf(s, w.y, acc.y);
    acc.z = fmaf(s, w.z, acc.z);
    acc.w = fmaf(s, w.w, acc.w);
}

// ---------------- register-tiled fp32 GEMM: out = relu?(X @ W + b) ----------
// BM=32 rows/block staged in LDS (double-buffered), each thread RPT rows x 4 cols.
// W streamed from L2 (hot), amortized over 32 rows -> VALU-bound, not L2-bound.
template<int K, int NC, bool RELU>
__global__ __launch_bounds__(256) void gemm_tiled(
    const float* __restrict__ X, int ldx,
    const float* __restrict__ W,              // K x NC row-major
    const float* __restrict__ bias,
    float* __restrict__ out, int ldo)
{
    constexpr int BM = 32, BK = 32, LS = BK + 4;   // LS pad: spread write banks
    constexpr int TPR = NC / 4;                    // threads covering NC cols
    constexpr int RG  = 256 / TPR;                 // row groups
    constexpr int RPT = BM / RG;                   // rows per thread
    constexpr int NFULL = K / BK;
    constexpr int KTAIL = K - NFULL * BK;

    __shared__ float sx[2][BM * LS];
    const int t = threadIdx.x;
    const size_t r0 = (size_t)blockIdx.x * BM;
    const int c4 = (t % TPR) * 4;
    const int rbase = (t / TPR) * RPT;
    const int lr = t >> 3;            // staging: row t/8
    const int lc = (t & 7) << 2;      // staging: col (t%8)*4

    const float4 bias4 = *(const float4*)&bias[c4];
    float4 acc[RPT];
    #pragma unroll
    for (int r = 0; r < RPT; ++r) acc[r] = make_float4(0.f, 0.f, 0.f, 0.f);

    if (NFULL > 0) {
        float4 stg = *(const float4*)&X[(r0 + lr) * ldx + lc];
        *(float4*)&sx[0][lr * LS + lc] = stg;
        __syncthreads();
        for (int c = 0; c < NFULL; ++c) {
            const int kc = c * BK;
            if (c + 1 < NFULL)   // issue next-chunk load early; latency hides under compute
                stg = *(const float4*)&X[(r0 + lr) * ldx + (kc + BK) + lc];
            const float* sb = &sx[c & 1][0];
            #pragma unroll
            for (int kk = 0; kk < BK; kk += 4) {
                const float* wp = &W[(size_t)(kc + kk) * NC + c4];
                float4 w0 = *(const float4*)(wp);
                float4 w1 = *(const float4*)(wp + NC);
                float4 w2 = *(const float4*)(wp + 2 * NC);
                float4 w3 = *(const float4*)(wp + 3 * NC);
                #pragma unroll
                for (int r = 0; r < RPT; ++r) {
                    float4 h = *(const float4*)&sb[(rbase + r) * LS + kk]; // wave-broadcast
                    fma4(acc[r], h.x, w0);
                    fma4(acc[r], h.y, w1);
                    fma4(acc[r], h.z, w2);
                    fma4(acc[r], h.w, w3);
                }
            }
            if (c + 1 < NFULL) {
                *(float4*)&sx[(c + 1) & 1][lr * LS + lc] = stg;  // other buffer: no pre-barrier
                __syncthreads();
            }
        }
    }
    if (KTAIL > 0) {
        __syncthreads();
        const int kc = NFULL * BK;
        float* sb = &sx[NFULL & 1][0];
        for (int i = t; i < BM * KTAIL; i += 256) {
            int rr = i / KTAIL, cc = i - rr * KTAIL;
            sb[rr * LS + cc] = X[(r0 + rr) * ldx + kc + cc];
        }
        __syncthreads();
        for (int kk = 0; kk < KTAIL; ++kk) {
            float4 w = *(const float4*)&W[(size_t)(kc + kk) * NC + c4];
            #pragma unroll
            for (int r = 0; r < RPT; ++r)
                fma4(acc[r], sb[(rbase + r) * LS + kk], w);
        }
    }
    #pragma unroll
    for (int r = 0; r < RPT; ++r) {
        float4 v;
        v.x = acc[r].x + bias4.x;
        v.y = acc[r].y + bias4.y;
        v.z = acc[r].z + bias4.z;
        v.w = acc[r].w + bias4.w;
        if (RELU) {
            v.x = fmaxf(v.x, 0.f); v.y = fmaxf(v.y, 0.f);
            v.z = fmaxf(v.z, 0.f); v.w = fmaxf(v.w, 0.f);
        }
        *(float4*)&out[(r0 + rbase + r) * (size_t)ldo + c4] = v;
    }
}

// ---------------- embedding gather + pool (sum over 4 lookups) --------------
__global__ __launch_bounds__(256) void embed_pool_kernel(
    const int* __restrict__ sidx, const float* __restrict__ tables,
    float* __restrict__ feats)
{
    const int wid = blockIdx.x * 4 + (threadIdx.x >> 6); // wave id = f*B + b
    const int lane = threadIdx.x & 63;
    const int f = wid >> 14;          // B = 16384 = 2^14
    const int b = wid & 16383;
    const int* ip = sidx + (size_t)wid * 4;
    const float* tab = tables + (size_t)f * NTAB * DIM;
    int i0 = ip[0], i1 = ip[1], i2 = ip[2], i3 = ip[3];
    float v0 = tab[(size_t)i0 * DIM + lane];
    float v1 = tab[(size_t)i1 * DIM + lane];
    float v2 = tab[(size_t)i2 * DIM + lane];
    float v3 = tab[(size_t)i3 * DIM + lane];
    feats[((size_t)b * NFEAT + 1 + f) * DIM + lane] = (v0 + v1) + (v2 + v3);
}

// ---------------- pairwise interaction + dense copy -> y --------------------
__global__ __launch_bounds__(256) void interact_kernel(
    const float* __restrict__ feats, float* __restrict__ y)
{
    __shared__ float sf[4 * NFEAT * 68]; // stride 68 spreads banks
    const int t = threadIdx.x;
    const size_t r0 = (size_t)blockIdx.x * 4;

    for (int i = t; i < 4 * NFEAT * DIM; i += 256) {
        int r = i / (NFEAT * DIM);
        int e = i - r * (NFEAT * DIM);
        int fi = e >> 6, d = e & 63;
        sf[r * (NFEAT * 68) + fi * 68 + d] = feats[r0 * (NFEAT * DIM) + i];
    }
    __syncthreads();

    // dense copy: y[:, 0:64]
    {
        int r = t >> 6, c = t & 63;
        y[(r0 + r) * YS + c] = sf[r * (NFEAT * 68) + c];
    }
    // pairs: y[:, 64:415]
    for (int w = t; w < 4 * NPAIRS; w += 256) {
        int r = w / NPAIRS, p = w - r * NPAIRS;
        int i = 0, pp = p;
        while (pp >= NF - i) { pp -= NF - i; ++i; }
        int j = i + 1 + pp;
        const float* fa = &sf[r * (NFEAT * 68) + i * 68];
        const float* fb = &sf[r * (NFEAT * 68) + j * 68];
        float acc = 0.0f;
        #pragma unroll
        for (int k = 0; k < DIM; k += 4) {
            float4 a = *(const float4*)&fa[k];
            float4 bv = *(const float4*)&fb[k];
            acc = fmaf(a.x, bv.x, acc);
            acc = fmaf(a.y, bv.y, acc);
            acc = fmaf(a.z, bv.z, acc);
            acc = fmaf(a.w, bv.w, acc);
        }
        y[(r0 + r) * YS + DIM + p] = acc;
    }
}

// ---------------- final 256 -> 1 layer (no relu) ----------------------------
__global__ __launch_bounds__(256) void top_final_kernel(
    const float* __restrict__ t1, const float* __restrict__ W2,
    const float* __restrict__ b2, float* __restrict__ out)
{
    const int wid = blockIdx.x * 4 + (threadIdx.x >> 6); // row
    const int lane = threadIdx.x & 63;
    const float4 w = ((const float4*)W2)[lane];
    const float4 v = ((const float4*)(t1 + (size_t)wid * 256))[lane];
    float acc = fmaf(v.x, w.x, fmaf(v.y, w.y, fmaf(v.z, w.z, v.w * w.w)));
    #pragma unroll
    for (int off = 32; off > 0; off >>= 1) acc += __shfl_down(acc, off, 64);
    if (lane == 0) out[wid] = acc + b2[0];
}

extern "C" void kernel_launch(void* const* d_in, const int* in_sizes, int n_in,
                              void* d_out, int out_size, void* d_ws, size_t ws_size,
                              hipStream_t stream)
{
    const float* dense = (const float*)d_in[0];
    const int*   sidx  = (const int*)d_in[1];
    const float* tabs  = (const float*)d_in[2];
    const float* bW0 = (const float*)d_in[3];  const float* bb0 = (const float*)d_in[4];
    const float* bW1 = (const float*)d_in[5];  const float* bb1 = (const float*)d_in[6];
    const float* bW2 = (const float*)d_in[7];  const float* bb2 = (const float*)d_in[8];
    const float* tW0 = (const float*)d_in[9];  const float* tb0 = (const float*)d_in[10];
    const float* tW1 = (const float*)d_in[11]; const float* tb1 = (const float*)d_in[12];
    const float* tW2 = (const float*)d_in[13]; const float* tb2 = (const float*)d_in[14];
    float* out = (float*)d_out;

    float* ws    = (float*)d_ws;
    float* feats = ws;                                   // B*27*64
    float* y     = feats + (size_t)BATCH * NFEAT * DIM;  // B*416
    float* bufA  = y     + (size_t)BATCH * YS;           // B*512 (h0, later t0)
    float* bufB  = bufA  + (size_t)BATCH * 512;          // B*256 (h1, later t1)

    const dim3 blk(256);
    const int gg = BATCH / 32;   // 512 blocks for the tiled GEMMs

    embed_pool_kernel<<<dim3(NF * BATCH / 4), blk, 0, stream>>>(sidx, tabs, feats);
    gemm_tiled<13, 512, true ><<<dim3(gg), blk, 0, stream>>>(dense, 13,  bW0, bb0, bufA, 512);
    gemm_tiled<512, 256, true><<<dim3(gg), blk, 0, stream>>>(bufA, 512, bW1, bb1, bufB, 256);
    gemm_tiled<256, 64, true ><<<dim3(gg), blk, 0, stream>>>(bufB, 256, bW2, bb2, feats, NFEAT * DIM);
    interact_kernel<<<dim3(BATCH / 4), blk, 0, stream>>>(feats, y);
    gemm_tiled<YK, 512, true ><<<dim3(gg), blk, 0, stream>>>(y, YS, tW0, tb0, bufA, 512);
    gemm_tiled<512, 256, true><<<dim3(gg), blk, 0, stream>>>(bufA, 512, tW1, tb1, bufB, 256);
    top_final_kernel<<<dim3(BATCH / 4), blk, 0, stream>>>(bufB, tW2, tb2, out);
}

// Round 10
// 1171.006 us; speedup vs baseline: 1.5425x; 1.4485x over previous
//
#include <hip/hip_runtime.h>

#define BATCH 16384
#define NF 26
#define NTAB 100000
#define DIM 64
#define NFEAT 27
#define NPAIRS 351
#define YS 416   // padded y row stride (float4-aligned)
#define YK 415   // true K of top layer 0

// ---------------- 2D-tiled fp32 GEMM: out = relu?(X @ W + b) ----------------
// A-tile (BMxBK, stored transposed As[k][m]) + B-tile (BKxBN) in LDS.
// 256 threads as TY x TX grid; each thread owns TM x TN outputs in registers.
// k-loop unroll capped at 4: bounds compiler load-hoisting (R4 spill lesson).
template<int K, int NC, int BM, int BN, int TM, int TN, bool RELU>
__global__ __launch_bounds__(256) void gemm2d(
    const float* __restrict__ X, int ldx,
    const float* __restrict__ W,              // K x NC row-major
    const float* __restrict__ bias,
    float* __restrict__ out, int ldo)
{
    constexpr int BK = 32;
    constexpr int LDA = BM + 4;
    constexpr int LDB = BN + 4;
    constexpr int TX = BN / TN;
    constexpr int TY = BM / TM;
    static_assert(TX * TY == 256, "thread grid");

    __shared__ float As[BK][LDA];
    __shared__ float Bs[BK][LDB];

    const int t  = threadIdx.x;
    const int tx = t % TX, ty = t / TX;
    const size_t r0  = (size_t)blockIdx.x * BM;
    const int    bn0 = blockIdx.y * BN;

    float acc[TM][TN];
    #pragma unroll
    for (int i = 0; i < TM; ++i)
        #pragma unroll
        for (int j = 0; j < TN; ++j) acc[i][j] = 0.0f;

    const int nkt = (K + BK - 1) / BK;
    for (int kt = 0; kt < nkt; ++kt) {
        const int kc = kt * BK;
        if (kc + BK <= K) {
            // vector staging. A: BM*BK/4 float4s, thread -> (m, k4)
            #pragma unroll
            for (int i = 0; i < (BM * BK) / (256 * 4); ++i) {
                int idx = t + i * 256;
                int m  = idx / (BK / 4);
                int k4 = (idx % (BK / 4)) * 4;
                float4 g = *(const float4*)&X[(r0 + m) * (size_t)ldx + kc + k4];
                As[k4 + 0][m] = g.x; As[k4 + 1][m] = g.y;
                As[k4 + 2][m] = g.z; As[k4 + 3][m] = g.w;
            }
            #pragma unroll
            for (int i = 0; i < (BK * BN) / (256 * 4); ++i) {
                int idx = t + i * 256;
                int k  = idx / (BN / 4);
                int n4 = (idx % (BN / 4)) * 4;
                *(float4*)&Bs[k][n4] = *(const float4*)&W[(size_t)(kc + k) * NC + bn0 + n4];
            }
        } else {
            // guarded scalar staging (K tails: 415, 13; also avoids unaligned f4)
            for (int i = t; i < BM * BK; i += 256) {
                int m = i / BK, k = i % BK;
                As[k][m] = (kc + k < K) ? X[(r0 + m) * (size_t)ldx + kc + k] : 0.0f;
            }
            for (int i = t; i < BK * BN; i += 256) {
                int k = i / BN, n = i % BN;
                Bs[k][n] = (kc + k < K) ? W[(size_t)(kc + k) * NC + bn0 + n] : 0.0f;
            }
        }
        __syncthreads();

        #pragma unroll 4
        for (int k = 0; k < BK; ++k) {
            float a[TM], b[TN];
            #pragma unroll
            for (int i = 0; i < TM; i += 4)
                *(float4*)&a[i] = *(const float4*)&As[k][ty * TM + i];  // broadcast across tx
            #pragma unroll
            for (int j = 0; j < TN; j += 4)
                *(float4*)&b[j] = *(const float4*)&Bs[k][tx * TN + j];
            #pragma unroll
            for (int i = 0; i < TM; ++i)
                #pragma unroll
                for (int j = 0; j < TN; ++j)
                    acc[i][j] = fmaf(a[i], b[j], acc[i][j]);
        }
        __syncthreads();
    }

    #pragma unroll
    for (int i = 0; i < TM; ++i) {
        const size_t orow = (r0 + ty * TM + i) * (size_t)ldo + bn0;
        #pragma unroll
        for (int j = 0; j < TN; j += 4) {
            float4 bi = *(const float4*)&bias[bn0 + tx * TN + j];
            float4 v;
            v.x = acc[i][j + 0] + bi.x;
            v.y = acc[i][j + 1] + bi.y;
            v.z = acc[i][j + 2] + bi.z;
            v.w = acc[i][j + 3] + bi.w;
            if (RELU) {
                v.x = fmaxf(v.x, 0.f); v.y = fmaxf(v.y, 0.f);
                v.z = fmaxf(v.z, 0.f); v.w = fmaxf(v.w, 0.f);
            }
            *(float4*)&out[orow + tx * TN + j] = v;
        }
    }
}

// ---------------- embedding gather + pool (sum over 4 lookups) --------------
__global__ __launch_bounds__(256) void embed_pool_kernel(
    const int* __restrict__ sidx, const float* __restrict__ tables,
    float* __restrict__ feats)
{
    const int wid = blockIdx.x * 4 + (threadIdx.x >> 6); // wave id = f*B + b
    const int lane = threadIdx.x & 63;
    const int f = wid >> 14;          // B = 16384 = 2^14
    const int b = wid & 16383;
    const int* ip = sidx + (size_t)wid * 4;
    const float* tab = tables + (size_t)f * NTAB * DIM;
    int i0 = ip[0], i1 = ip[1], i2 = ip[2], i3 = ip[3];
    float v0 = tab[(size_t)i0 * DIM + lane];
    float v1 = tab[(size_t)i1 * DIM + lane];
    float v2 = tab[(size_t)i2 * DIM + lane];
    float v3 = tab[(size_t)i3 * DIM + lane];
    feats[((size_t)b * NFEAT + 1 + f) * DIM + lane] = (v0 + v1) + (v2 + v3);
}

// ---------------- pairwise interaction + dense copy -> y --------------------
__global__ __launch_bounds__(256) void interact_kernel(
    const float* __restrict__ feats, float* __restrict__ y)
{
    __shared__ float sf[4 * NFEAT * 68]; // stride 68 spreads banks
    const int t = threadIdx.x;
    const size_t r0 = (size_t)blockIdx.x * 4;

    for (int i = t; i < 4 * NFEAT * DIM; i += 256) {
        int r = i / (NFEAT * DIM);
        int e = i - r * (NFEAT * DIM);
        int fi = e >> 6, d = e & 63;
        sf[r * (NFEAT * 68) + fi * 68 + d] = feats[r0 * (NFEAT * DIM) + i];
    }
    __syncthreads();

    // dense copy: y[:, 0:64]
    {
        int r = t >> 6, c = t & 63;
        y[(r0 + r) * YS + c] = sf[r * (NFEAT * 68) + c];
    }
    // pairs: y[:, 64:415]
    for (int w = t; w < 4 * NPAIRS; w += 256) {
        int r = w / NPAIRS, p = w - r * NPAIRS;
        int i = 0, pp = p;
        while (pp >= NF - i) { pp -= NF - i; ++i; }
        int j = i + 1 + pp;
        const float* fa = &sf[r * (NFEAT * 68) + i * 68];
        const float* fb = &sf[r * (NFEAT * 68) + j * 68];
        float acc = 0.0f;
        #pragma unroll
        for (int k = 0; k < DIM; k += 4) {
            float4 a = *(const float4*)&fa[k];
            float4 bv = *(const float4*)&fb[k];
            acc = fmaf(a.x, bv.x, acc);
            acc = fmaf(a.y, bv.y, acc);
            acc = fmaf(a.z, bv.z, acc);
            acc = fmaf(a.w, bv.w, acc);
        }
        y[(r0 + r) * YS + DIM + p] = acc;
    }
}

// ---------------- final 256 -> 1 layer (no relu) ----------------------------
__global__ __launch_bounds__(256) void top_final_kernel(
    const float* __restrict__ t1, const float* __restrict__ W2,
    const float* __restrict__ b2, float* __restrict__ out)
{
    const int wid = blockIdx.x * 4 + (threadIdx.x >> 6); // row
    const int lane = threadIdx.x & 63;
    const float4 w = ((const float4*)W2)[lane];
    const float4 v = ((const float4*)(t1 + (size_t)wid * 256))[lane];
    float acc = fmaf(v.x, w.x, fmaf(v.y, w.y, fmaf(v.z, w.z, v.w * w.w)));
    #pragma unroll
    for (int off = 32; off > 0; off >>= 1) acc += __shfl_down(acc, off, 64);
    if (lane == 0) out[wid] = acc + b2[0];
}

extern "C" void kernel_launch(void* const* d_in, const int* in_sizes, int n_in,
                              void* d_out, int out_size, void* d_ws, size_t ws_size,
                              hipStream_t stream)
{
    const float* dense = (const float*)d_in[0];
    const int*   sidx  = (const int*)d_in[1];
    const float* tabs  = (const float*)d_in[2];
    const float* bW0 = (const float*)d_in[3];  const float* bb0 = (const float*)d_in[4];
    const float* bW1 = (const float*)d_in[5];  const float* bb1 = (const float*)d_in[6];
    const float* bW2 = (const float*)d_in[7];  const float* bb2 = (const float*)d_in[8];
    const float* tW0 = (const float*)d_in[9];  const float* tb0 = (const float*)d_in[10];
    const float* tW1 = (const float*)d_in[11]; const float* tb1 = (const float*)d_in[12];
    const float* tW2 = (const float*)d_in[13]; const float* tb2 = (const float*)d_in[14];
    float* out = (float*)d_out;

    float* ws    = (float*)d_ws;
    float* feats = ws;                                   // B*27*64
    float* y     = feats + (size_t)BATCH * NFEAT * DIM;  // B*416
    float* bufA  = y     + (size_t)BATCH * YS;           // B*512 (h0, later t0)
    float* bufB  = bufA  + (size_t)BATCH * 512;          // B*256 (h1, later t1)

    const dim3 blk(256);

    embed_pool_kernel<<<dim3(NF * BATCH / 4), blk, 0, stream>>>(sidx, tabs, feats);

    // bottom MLP: 13 -> 512 -> 256 -> 64
    gemm2d<13, 512, 128, 128, 8, 8, true>
        <<<dim3(BATCH / 128, 4), blk, 0, stream>>>(dense, 13, bW0, bb0, bufA, 512);
    gemm2d<512, 256, 128, 64, 8, 4, true>
        <<<dim3(BATCH / 128, 4), blk, 0, stream>>>(bufA, 512, bW1, bb1, bufB, 256);
    gemm2d<256, 64, 64, 64, 4, 4, true>
        <<<dim3(BATCH / 64, 1), blk, 0, stream>>>(bufB, 256, bW2, bb2, feats, NFEAT * DIM);

    interact_kernel<<<dim3(BATCH / 4), blk, 0, stream>>>(feats, y);

    // top MLP: 415 -> 512 -> 256 -> 1
    gemm2d<YK, 512, 128, 128, 8, 8, true>
        <<<dim3(BATCH / 128, 4), blk, 0, stream>>>(y, YS, tW0, tb0, bufA, 512);
    gemm2d<512, 256, 128, 64, 8, 4, true>
        <<<dim3(BATCH / 128, 4), blk, 0, stream>>>(bufA, 512, tW1, tb1, bufB, 256);
    top_final_kernel<<<dim3(BATCH / 4), blk, 0, stream>>>(bufB, tW2, tb2, out);
}